// Round 5
// baseline (412.585 us; speedup 1.0000x reference)
//
#include <hip/hip_runtime.h>
#include <hip/hip_fp16.h>

#define NEG_SLOPE 0.2f
#define GAT_EPS 1e-16f

// ---- prep: w2as = W2 @ a_src2, w2ad = W2 @ a_dst2 (W2 is [64,128] row-major) ----
__global__ __launch_bounds__(128) void prep_kernel(
    const float* __restrict__ W2, const float* __restrict__ a_s2,
    const float* __restrict__ a_d2, float* __restrict__ w2as,
    float* __restrict__ w2ad) {
  const int t = threadIdx.x;  // 128 threads
  const int c = t & 63;
  const float* av = (t < 64) ? a_s2 : a_d2;
  float s = 0.f;
  for (int j = 0; j < 128; ++j) s = fmaf(W2[c * 128 + j], av[j], s);
  if (t < 64) w2as[c] = s; else w2ad[c] = s;
}

// ---- GEMM1 (persistent): h1 = x @ W1 (128 -> 64) as fp16 + alpha reductions ----
__global__ __launch_bounds__(256) void gemm1_kernel(
    const float* __restrict__ x, const float* __restrict__ W1,
    const float* __restrict__ a_src, const float* __restrict__ a_dst,
    __half* __restrict__ h16, float* __restrict__ as_out,
    float* __restrict__ ad_out, int N) {
  __shared__ float Wl[128 * 64];   // 32 KB, loaded once
  __shared__ float xs[16][128];    // 8 KB per tile
  const int t = threadIdx.x;
  {
    const float4* Wv = (const float4*)W1;
    float4* Wd = (float4*)Wl;
    for (int i = t; i < 128 * 64 / 4; i += 256) Wd[i] = Wv[i];
  }
  const int wave = t >> 6, lane = t & 63;
  const int wr = wave * 4;
  const float asl = a_src[lane], adl = a_dst[lane];
  const int ntiles = (N + 15) / 16;
  for (int tile = blockIdx.x; tile < ntiles; tile += gridDim.x) {
    const int base = tile * 16;
    __syncthreads();
    {
      const float4* Xv = (const float4*)(x + (size_t)base * 128);
      float4* Xd = (float4*)xs;
      int lim = (base + 16 <= N) ? 16 * 128 / 4 : ((N - base) * 128) / 4;
      for (int i = t; i < lim; i += 256) Xd[i] = Xv[i];
    }
    __syncthreads();
    float acc[4] = {0.f, 0.f, 0.f, 0.f};
    for (int kq = 0; kq < 128; kq += 4) {
      float4 x0 = *(const float4*)&xs[wr + 0][kq];
      float4 x1 = *(const float4*)&xs[wr + 1][kq];
      float4 x2 = *(const float4*)&xs[wr + 2][kq];
      float4 x3 = *(const float4*)&xs[wr + 3][kq];
      float w0 = Wl[(kq + 0) * 64 + lane];
      float w1 = Wl[(kq + 1) * 64 + lane];
      float w2 = Wl[(kq + 2) * 64 + lane];
      float w3 = Wl[(kq + 3) * 64 + lane];
      acc[0] = fmaf(x0.x, w0, acc[0]); acc[0] = fmaf(x0.y, w1, acc[0]);
      acc[0] = fmaf(x0.z, w2, acc[0]); acc[0] = fmaf(x0.w, w3, acc[0]);
      acc[1] = fmaf(x1.x, w0, acc[1]); acc[1] = fmaf(x1.y, w1, acc[1]);
      acc[1] = fmaf(x1.z, w2, acc[1]); acc[1] = fmaf(x1.w, w3, acc[1]);
      acc[2] = fmaf(x2.x, w0, acc[2]); acc[2] = fmaf(x2.y, w1, acc[2]);
      acc[2] = fmaf(x2.z, w2, acc[2]); acc[2] = fmaf(x2.w, w3, acc[2]);
      acc[3] = fmaf(x3.x, w0, acc[3]); acc[3] = fmaf(x3.y, w1, acc[3]);
      acc[3] = fmaf(x3.z, w2, acc[3]); acc[3] = fmaf(x3.w, w3, acc[3]);
    }
#pragma unroll
    for (int r = 0; r < 4; ++r) {
      const int row = base + wr + r;
      if (row >= N) break;
      h16[(size_t)row * 64 + lane] = __float2half(acc[r]);
      float va = acc[r] * asl;
      float vd = acc[r] * adl;
#pragma unroll
      for (int off = 32; off > 0; off >>= 1) {
        va += __shfl_down(va, off, 64);
        vd += __shfl_down(vd, off, 64);
      }
      if (lane == 0) { as_out[row] = va; ad_out[row] = vd; }
    }
  }
}

// ---- CSR build: histogram of dst (self-loops appended implicitly) ----
__global__ __launch_bounds__(256) void hist_kernel(
    const int* __restrict__ dsts, int E, int ET, int* __restrict__ count) {
  for (int i = blockIdx.x * blockDim.x + threadIdx.x; i < ET;
       i += gridDim.x * blockDim.x) {
    int d = (i < E) ? dsts[i] : i - E;
    atomicAdd(count + d, 1);
  }
}

__global__ __launch_bounds__(256) void scan_blocks_kernel(
    const int* __restrict__ count, int* __restrict__ row_ptr,
    int* __restrict__ bsums, int N) {
  __shared__ int sd[256];
  const int t = threadIdx.x;
  const int i = blockIdx.x * 256 + t;
  int v = (i < N) ? count[i] : 0;
  sd[t] = v;
  __syncthreads();
  for (int off = 1; off < 256; off <<= 1) {
    int add = (t >= off) ? sd[t - off] : 0;
    __syncthreads();
    sd[t] += add;
    __syncthreads();
  }
  if (i < N) row_ptr[i] = sd[t] - v;  // exclusive, partial
  if (t == 255) bsums[blockIdx.x] = sd[255];
}

__global__ __launch_bounds__(256) void scan_top_kernel(int* __restrict__ bsums,
                                                       int nblk) {
  __shared__ int sd[256];
  const int t = threadIdx.x;
  int v = (t < nblk) ? bsums[t] : 0;
  sd[t] = v;
  __syncthreads();
  for (int off = 1; off < 256; off <<= 1) {
    int add = (t >= off) ? sd[t - off] : 0;
    __syncthreads();
    sd[t] += add;
    __syncthreads();
  }
  if (t < nblk) bsums[t] = sd[t] - v;  // exclusive
}

__global__ __launch_bounds__(256) void scan_add_kernel(
    int* __restrict__ row_ptr, const int* __restrict__ bsums,
    int* __restrict__ next, int N, int ET) {
  const int i = blockIdx.x * 256 + threadIdx.x;
  if (i < N) {
    int v = row_ptr[i] + bsums[blockIdx.x];
    row_ptr[i] = v;
    next[i] = v;
  }
  if (i == 0) row_ptr[N] = ET;
}

// ---- scatter edges into dst-sorted order + fused layer-1 edge weights ----
__global__ __launch_bounds__(256) void scatter_pe1_kernel(
    const int* __restrict__ srcs, const int* __restrict__ dsts, int E, int ET,
    int* __restrict__ next, const float* __restrict__ as1,
    const float* __restrict__ ad1, int* __restrict__ ssrc,
    int* __restrict__ sdst, float* __restrict__ pe) {
  for (int i = blockIdx.x * blockDim.x + threadIdx.x; i < ET;
       i += gridDim.x * blockDim.x) {
    int s, d;
    if (i < E) { s = srcs[i]; d = dsts[i]; } else { s = d = i - E; }
    int pos = atomicAdd(next + d, 1);
    ssrc[pos] = s;
    sdst[pos] = d;
    float e = as1[s] + ad1[d];
    e = e > 0.f ? e : NEG_SLOPE * e;
    pe[pos] = __expf(e);
  }
}

// ---- layer-2 edge weights (sorted order) ----
__global__ __launch_bounds__(256) void edge_p2_kernel(
    const int* __restrict__ ssrc, const int* __restrict__ sdst, int ET,
    const float* __restrict__ as2, const float* __restrict__ ad2,
    float* __restrict__ pe) {
  for (int i = blockIdx.x * blockDim.x + threadIdx.x; i < ET;
       i += gridDim.x * blockDim.x) {
    float e = as2[ssrc[i]] + ad2[sdst[i]];
    e = e > 0.f ? e : NEG_SLOPE * e;
    pe[i] = __expf(e);
  }
}

// ---- fused per-node aggregation: one wave/node, 2 edges per iter (half-wave
// split), packed __half2 gathers, 2x unroll -> 4 gathers in flight ----
template <int LAYER>
__global__ __launch_bounds__(256) void node_agg_kernel(
    const int* __restrict__ row_ptr, const int* __restrict__ ssrc,
    const float* __restrict__ pe, const __half* __restrict__ hsrc,
    const float* __restrict__ b1, const float* __restrict__ w2as,
    const float* __restrict__ w2ad, __half* __restrict__ rl1,
    float* __restrict__ as2, float* __restrict__ ad2,
    float* __restrict__ agg2, int N) {
  const int lane = threadIdx.x & 63;
  const int half = lane >> 5;       // 0: even edges, 1: odd edges
  const int hl = lane & 31;         // feature pair index
  const int node = blockIdx.x * 4 + (threadIdx.x >> 6);
  if (node >= N) return;
  const int beg = row_ptr[node], end = row_ptr[node + 1];

  float acc0 = 0.f, acc1 = 0.f, acc0b = 0.f, acc1b = 0.f, Sl = 0.f, Slb = 0.f;
  int j = beg + half;
  for (; j + 2 < end; j += 4) {
    int s0 = ssrc[j];
    int s1 = ssrc[j + 2];
    float p0 = pe[j];
    float p1 = pe[j + 2];
    float2 f0 = __half22float2(*(const __half2*)(hsrc + (size_t)s0 * 64 + 2 * hl));
    float2 f1 = __half22float2(*(const __half2*)(hsrc + (size_t)s1 * 64 + 2 * hl));
    acc0  = fmaf(p0, f0.x, acc0);  acc1  = fmaf(p0, f0.y, acc1);  Sl  += p0;
    acc0b = fmaf(p1, f1.x, acc0b); acc1b = fmaf(p1, f1.y, acc1b); Slb += p1;
  }
  if (j < end) {
    int s0 = ssrc[j];
    float p0 = pe[j];
    float2 f0 = __half22float2(*(const __half2*)(hsrc + (size_t)s0 * 64 + 2 * hl));
    acc0 = fmaf(p0, f0.x, acc0); acc1 = fmaf(p0, f0.y, acc1); Sl += p0;
  }
  acc0 += acc0b; acc1 += acc1b; Sl += Slb;
  acc0 += __shfl_xor(acc0, 32, 64);
  acc1 += __shfl_xor(acc1, 32, 64);
  Sl   += __shfl_xor(Sl, 32, 64);
  const float inv = 1.f / (Sl + GAT_EPS);

  if (LAYER == 1) {
    float2 bb = ((const float2*)b1)[hl];
    float r0 = fmaxf(fmaf(acc0, inv, bb.x), 0.f);
    float r1 = fmaxf(fmaf(acc1, inv, bb.y), 0.f);
    if (half == 0)
      *(__half2*)(rl1 + (size_t)node * 64 + 2 * hl) = __floats2half2_rn(r0, r1);
    float2 was = ((const float2*)w2as)[hl];
    float2 wad = ((const float2*)w2ad)[hl];
    float va = fmaf(r0, was.x, r1 * was.y);
    float vd = fmaf(r0, wad.x, r1 * wad.y);
#pragma unroll
    for (int off = 16; off > 0; off >>= 1) {
      va += __shfl_xor(va, off, 64);
      vd += __shfl_xor(vd, off, 64);
    }
    if (lane == 0) { as2[node] = va; ad2[node] = vd; }
  } else {
    if (half == 0) {
      float2 o; o.x = acc0 * inv; o.y = acc1 * inv;
      *(float2*)(agg2 + (size_t)node * 64 + 2 * hl) = o;
    }
  }
}

// ---- final GEMM (persistent): out = agg2 @ W2 + b2 (64 -> 128) ----
__global__ __launch_bounds__(256) void gemm_out_kernel(
    const float* __restrict__ agg2, const float* __restrict__ W2,
    const float* __restrict__ b2, float* __restrict__ out, int N) {
  __shared__ float Wl[64 * 128];  // 32 KB, loaded once
  __shared__ float xs[16][64];    // 4 KB per tile
  const int t = threadIdx.x;
  {
    const float4* Wv = (const float4*)W2;
    float4* Wd = (float4*)Wl;
    for (int i = t; i < 64 * 128 / 4; i += 256) Wd[i] = Wv[i];
  }
  const int wave = t >> 6, lane = t & 63;
  const int rg = wave >> 1;                // row group 0..1 (8 rows each)
  const int col = (wave & 1) * 64 + lane;  // 0..127
  const float bc = b2[col];
  const int ntiles = (N + 15) / 16;
  for (int tile = blockIdx.x; tile < ntiles; tile += gridDim.x) {
    const int base = tile * 16;
    __syncthreads();
    {
      const float4* Xv = (const float4*)(agg2 + (size_t)base * 64);
      float4* Xd = (float4*)xs;
      int lim = (base + 16 <= N) ? 16 * 64 / 4 : ((N - base) * 64) / 4;
      for (int i = t; i < lim; i += 256) Xd[i] = Xv[i];
    }
    __syncthreads();
    float acc[8];
#pragma unroll
    for (int r = 0; r < 8; ++r) acc[r] = bc;
    for (int kq = 0; kq < 64; kq += 4) {
      float w0 = Wl[(kq + 0) * 128 + col];
      float w1 = Wl[(kq + 1) * 128 + col];
      float w2 = Wl[(kq + 2) * 128 + col];
      float w3 = Wl[(kq + 3) * 128 + col];
#pragma unroll
      for (int r = 0; r < 8; ++r) {
        float4 xv = *(const float4*)&xs[rg * 8 + r][kq];
        acc[r] = fmaf(xv.x, w0, acc[r]);
        acc[r] = fmaf(xv.y, w1, acc[r]);
        acc[r] = fmaf(xv.z, w2, acc[r]);
        acc[r] = fmaf(xv.w, w3, acc[r]);
      }
    }
#pragma unroll
    for (int r = 0; r < 8; ++r) {
      const int row = base + rg * 8 + r;
      if (row < N) out[(size_t)row * 128 + col] = acc[r];
    }
  }
}

extern "C" void kernel_launch(void* const* d_in, const int* in_sizes, int n_in,
                              void* d_out, int out_size, void* d_ws, size_t ws_size,
                              hipStream_t stream) {
  const float* x    = (const float*)d_in[0];
  const int*   ei   = (const int*)d_in[1];
  const float* W1   = (const float*)d_in[2];
  const float* a_s1 = (const float*)d_in[3];
  const float* a_d1 = (const float*)d_in[4];
  const float* b1   = (const float*)d_in[5];
  const float* W2   = (const float*)d_in[6];
  const float* a_s2 = (const float*)d_in[7];
  const float* a_d2 = (const float*)d_in[8];
  const float* b2   = (const float*)d_in[9];

  const int N  = in_sizes[0] / 128;
  const int E  = in_sizes[1] / 2;
  const int ET = E + N;
  const int* srcs = ei;
  const int* dsts = ei + E;
  const int nblk = (N + 255) / 256;

  // workspace layout
  char* w = (char*)d_ws;
  __half* h16  = (__half*)w;            w += (size_t)N * 64 * 2;
  __half* rl1  = (__half*)w;            w += (size_t)N * 64 * 2;
  float* agg2  = (float*)w;             w += (size_t)N * 64 * 4;
  float* as1   = (float*)w;             w += (size_t)N * 4;
  float* ad1   = (float*)w;             w += (size_t)N * 4;
  float* as2   = (float*)w;             w += (size_t)N * 4;
  float* ad2   = (float*)w;             w += (size_t)N * 4;
  float* w2as  = (float*)w;             w += 64 * 4;
  float* w2ad  = (float*)w;             w += 64 * 4;
  int* row_ptr = (int*)w;               w += (size_t)(N + 1) * 4;
  int* next    = (int*)w;               w += (size_t)N * 4;
  int* ssrc    = (int*)w;               w += (size_t)ET * 4;
  int* sdst    = (int*)w;               w += (size_t)ET * 4;
  float* pe    = (float*)w;             w += (size_t)ET * 4;
  int* bsums   = (int*)w;               w += (size_t)nblk * 4;
  int* count   = next;  // alias: histogram is dead after scan

  float* out = (float*)d_out;  // N*128

  // ---- build CSR skeleton (independent of features) ----
  hipMemsetAsync(count, 0, (size_t)N * sizeof(int), stream);
  hist_kernel<<<2048, 256, 0, stream>>>(dsts, E, ET, count);
  scan_blocks_kernel<<<nblk, 256, 0, stream>>>(count, row_ptr, bsums, N);
  scan_top_kernel<<<1, 256, 0, stream>>>(bsums, nblk);
  scan_add_kernel<<<nblk, 256, 0, stream>>>(row_ptr, bsums, next, N, ET);

  // ---- weights prep + layer-1 features ----
  prep_kernel<<<1, 128, 0, stream>>>(W2, a_s2, a_d2, w2as, w2ad);
  gemm1_kernel<<<1024, 256, 0, stream>>>(x, W1, a_s1, a_d1, h16, as1, ad1, N);
  // ---- scatter (sorted adjacency) + layer-1 edge weights ----
  scatter_pe1_kernel<<<2048, 256, 0, stream>>>(srcs, dsts, E, ET, next, as1, ad1,
                                               ssrc, sdst, pe);
  // ---- layer-1 aggregation ----
  node_agg_kernel<1><<<(N + 3) / 4, 256, 0, stream>>>(
      row_ptr, ssrc, pe, h16, b1, w2as, w2ad, rl1, as2, ad2, (float*)nullptr, N);
  // ---- layer-2 edge weights + aggregation (64-dim, W2 commuted out) ----
  edge_p2_kernel<<<2048, 256, 0, stream>>>(ssrc, sdst, ET, as2, ad2, pe);
  node_agg_kernel<2><<<(N + 3) / 4, 256, 0, stream>>>(
      row_ptr, ssrc, pe, rl1, b1, w2as, w2ad, ((__half*)nullptr), as2, ad2,
      agg2, N);
  // ---- final GEMM ----
  gemm_out_kernel<<<1024, 256, 0, stream>>>(agg2, W2, b2, out, N);
}

// Round 6
// 310.809 us; speedup vs baseline: 1.3275x; 1.3275x over previous
//
#include <hip/hip_runtime.h>
#include <hip/hip_fp16.h>

#define NEG_SLOPE 0.2f
#define GAT_EPS 1e-16f

// ---- prep: w2as = W2 @ a_src2, w2ad = W2 @ a_dst2 (W2 is [64,128] row-major) ----
__global__ __launch_bounds__(128) void prep_kernel(
    const float* __restrict__ W2, const float* __restrict__ a_s2,
    const float* __restrict__ a_d2, float* __restrict__ w2as,
    float* __restrict__ w2ad) {
  const int t = threadIdx.x;  // 128 threads
  const int c = t & 63;
  const float* av = (t < 64) ? a_s2 : a_d2;
  float s = 0.f;
  for (int j = 0; j < 128; ++j) s = fmaf(W2[c * 128 + j], av[j], s);
  if (t < 64) w2as[c] = s; else w2ad[c] = s;
}

// ---- GEMM1: h1 = x @ W1 (128 -> 64) as fp16 + alpha reductions ----
// Wave-uniform rows: X via scalar loads (SMEM pipe), W via LDS b32, 4 rows/wave.
// No __syncthreads in the main loop.
__global__ __launch_bounds__(256) void gemm1_kernel(
    const float* __restrict__ x, const float* __restrict__ W1,
    const float* __restrict__ a_src, const float* __restrict__ a_dst,
    __half* __restrict__ h16, float* __restrict__ as_out,
    float* __restrict__ ad_out, int N) {
  __shared__ float Wl[128 * 64];  // 32 KB, loaded once
  const int t = threadIdx.x;
  {
    const float4* Wv = (const float4*)W1;
    float4* Wd = (float4*)Wl;
    for (int i = t; i < 128 * 64 / 4; i += 256) Wd[i] = Wv[i];
  }
  __syncthreads();
  const int lane = t & 63;
  // wave-uniform wave id -> uniform row pointers -> scalar (SGPR) x loads
  const int wid = __builtin_amdgcn_readfirstlane(blockIdx.x * 4 + (t >> 6));
  const int nwaves = gridDim.x * 4;
  const float asl = a_src[lane], adl = a_dst[lane];
  for (int row4 = wid * 4; row4 < N; row4 += nwaves * 4) {
    const int r0 = row4;
    const int r1 = min(row4 + 1, N - 1);
    const int r2 = min(row4 + 2, N - 1);
    const int r3 = min(row4 + 3, N - 1);
    const float* __restrict__ x0 = x + (size_t)r0 * 128;
    const float* __restrict__ x1 = x + (size_t)r1 * 128;
    const float* __restrict__ x2 = x + (size_t)r2 * 128;
    const float* __restrict__ x3 = x + (size_t)r3 * 128;
    float a0 = 0.f, a1 = 0.f, a2 = 0.f, a3 = 0.f;
#pragma unroll 8
    for (int k = 0; k < 128; ++k) {
      float wv = Wl[k * 64 + lane];
      a0 = fmaf(x0[k], wv, a0);
      a1 = fmaf(x1[k], wv, a1);
      a2 = fmaf(x2[k], wv, a2);
      a3 = fmaf(x3[k], wv, a3);
    }
    float acc[4] = {a0, a1, a2, a3};
#pragma unroll
    for (int r = 0; r < 4; ++r) {
      const int row = row4 + r;
      if (row >= N) break;
      h16[(size_t)row * 64 + lane] = __float2half(acc[r]);
      float va = acc[r] * asl;
      float vd = acc[r] * adl;
#pragma unroll
      for (int off = 32; off > 0; off >>= 1) {
        va += __shfl_down(va, off, 64);
        vd += __shfl_down(vd, off, 64);
      }
      if (lane == 0) { as_out[row] = va; ad_out[row] = vd; }
    }
  }
}

// ---- CSR build: histogram of dst (self-loops appended implicitly) ----
__global__ __launch_bounds__(256) void hist_kernel(
    const int* __restrict__ dsts, int E, int ET, int* __restrict__ count) {
  for (int i = blockIdx.x * blockDim.x + threadIdx.x; i < ET;
       i += gridDim.x * blockDim.x) {
    int d = (i < E) ? dsts[i] : i - E;
    atomicAdd(count + d, 1);
  }
}

__global__ __launch_bounds__(256) void scan_blocks_kernel(
    const int* __restrict__ count, int* __restrict__ row_ptr,
    int* __restrict__ bsums, int N) {
  __shared__ int sd[256];
  const int t = threadIdx.x;
  const int i = blockIdx.x * 256 + t;
  int v = (i < N) ? count[i] : 0;
  sd[t] = v;
  __syncthreads();
  for (int off = 1; off < 256; off <<= 1) {
    int add = (t >= off) ? sd[t - off] : 0;
    __syncthreads();
    sd[t] += add;
    __syncthreads();
  }
  if (i < N) row_ptr[i] = sd[t] - v;  // exclusive, partial
  if (t == 255) bsums[blockIdx.x] = sd[255];
}

__global__ __launch_bounds__(256) void scan_top_kernel(int* __restrict__ bsums,
                                                       int nblk) {
  __shared__ int sd[256];
  const int t = threadIdx.x;
  int v = (t < nblk) ? bsums[t] : 0;
  sd[t] = v;
  __syncthreads();
  for (int off = 1; off < 256; off <<= 1) {
    int add = (t >= off) ? sd[t - off] : 0;
    __syncthreads();
    sd[t] += add;
    __syncthreads();
  }
  if (t < nblk) bsums[t] = sd[t] - v;  // exclusive
}

__global__ __launch_bounds__(256) void scan_add_kernel(
    int* __restrict__ row_ptr, const int* __restrict__ bsums,
    int* __restrict__ next, int N, int ET) {
  const int i = blockIdx.x * 256 + threadIdx.x;
  if (i < N) {
    int v = row_ptr[i] + bsums[blockIdx.x];
    row_ptr[i] = v;
    next[i] = v;
  }
  if (i == 0) row_ptr[N] = ET;
}

// ---- scatter edges into dst-sorted order + fused layer-1 edge weights ----
__global__ __launch_bounds__(256) void scatter_pe1_kernel(
    const int* __restrict__ srcs, const int* __restrict__ dsts, int E, int ET,
    int* __restrict__ next, const float* __restrict__ as1,
    const float* __restrict__ ad1, int* __restrict__ ssrc,
    int* __restrict__ sdst, float* __restrict__ pe) {
  for (int i = blockIdx.x * blockDim.x + threadIdx.x; i < ET;
       i += gridDim.x * blockDim.x) {
    int s, d;
    if (i < E) { s = srcs[i]; d = dsts[i]; } else { s = d = i - E; }
    int pos = atomicAdd(next + d, 1);
    ssrc[pos] = s;
    sdst[pos] = d;
    float e = as1[s] + ad1[d];
    e = e > 0.f ? e : NEG_SLOPE * e;
    pe[pos] = __expf(e);
  }
}

// ---- layer-2 edge weights (sorted order) ----
__global__ __launch_bounds__(256) void edge_p2_kernel(
    const int* __restrict__ ssrc, const int* __restrict__ sdst, int ET,
    const float* __restrict__ as2, const float* __restrict__ ad2,
    float* __restrict__ pe) {
  for (int i = blockIdx.x * blockDim.x + threadIdx.x; i < ET;
       i += gridDim.x * blockDim.x) {
    float e = as2[ssrc[i]] + ad2[sdst[i]];
    e = e > 0.f ? e : NEG_SLOPE * e;
    pe[i] = __expf(e);
  }
}

// ---- fused per-node aggregation: one wave/node, 2 edges per iter (half-wave
// split), packed __half2 gathers, 2x unroll -> 4 gathers in flight ----
template <int LAYER>
__global__ __launch_bounds__(256) void node_agg_kernel(
    const int* __restrict__ row_ptr, const int* __restrict__ ssrc,
    const float* __restrict__ pe, const __half* __restrict__ hsrc,
    const float* __restrict__ b1, const float* __restrict__ w2as,
    const float* __restrict__ w2ad, __half* __restrict__ rl1,
    float* __restrict__ as2, float* __restrict__ ad2,
    float* __restrict__ agg2, int N) {
  const int lane = threadIdx.x & 63;
  const int half = lane >> 5;       // 0: even edges, 1: odd edges
  const int hl = lane & 31;         // feature pair index
  const int node = blockIdx.x * 4 + (threadIdx.x >> 6);
  if (node >= N) return;
  const int beg = row_ptr[node], end = row_ptr[node + 1];

  float acc0 = 0.f, acc1 = 0.f, acc0b = 0.f, acc1b = 0.f, Sl = 0.f, Slb = 0.f;
  int j = beg + half;
  for (; j + 2 < end; j += 4) {
    int s0 = ssrc[j];
    int s1 = ssrc[j + 2];
    float p0 = pe[j];
    float p1 = pe[j + 2];
    float2 f0 = __half22float2(*(const __half2*)(hsrc + (size_t)s0 * 64 + 2 * hl));
    float2 f1 = __half22float2(*(const __half2*)(hsrc + (size_t)s1 * 64 + 2 * hl));
    acc0  = fmaf(p0, f0.x, acc0);  acc1  = fmaf(p0, f0.y, acc1);  Sl  += p0;
    acc0b = fmaf(p1, f1.x, acc0b); acc1b = fmaf(p1, f1.y, acc1b); Slb += p1;
  }
  if (j < end) {
    int s0 = ssrc[j];
    float p0 = pe[j];
    float2 f0 = __half22float2(*(const __half2*)(hsrc + (size_t)s0 * 64 + 2 * hl));
    acc0 = fmaf(p0, f0.x, acc0); acc1 = fmaf(p0, f0.y, acc1); Sl += p0;
  }
  acc0 += acc0b; acc1 += acc1b; Sl += Slb;
  acc0 += __shfl_xor(acc0, 32, 64);
  acc1 += __shfl_xor(acc1, 32, 64);
  Sl   += __shfl_xor(Sl, 32, 64);
  const float inv = 1.f / (Sl + GAT_EPS);

  if (LAYER == 1) {
    float2 bb = ((const float2*)b1)[hl];
    float r0 = fmaxf(fmaf(acc0, inv, bb.x), 0.f);
    float r1 = fmaxf(fmaf(acc1, inv, bb.y), 0.f);
    if (half == 0)
      *(__half2*)(rl1 + (size_t)node * 64 + 2 * hl) = __floats2half2_rn(r0, r1);
    float2 was = ((const float2*)w2as)[hl];
    float2 wad = ((const float2*)w2ad)[hl];
    float va = fmaf(r0, was.x, r1 * was.y);
    float vd = fmaf(r0, wad.x, r1 * wad.y);
#pragma unroll
    for (int off = 16; off > 0; off >>= 1) {
      va += __shfl_xor(va, off, 64);
      vd += __shfl_xor(vd, off, 64);
    }
    if (lane == 0) { as2[node] = va; ad2[node] = vd; }
  } else {
    if (half == 0) {
      float2 o; o.x = acc0 * inv; o.y = acc1 * inv;
      *(float2*)(agg2 + (size_t)node * 64 + 2 * hl) = o;
    }
  }
}

// ---- final GEMM: out = agg2 @ W2 + b2 (64 -> 128) ----
// Wave-pair-uniform rows: X via scalar loads, W via LDS b32, 4 rows/wave.
__global__ __launch_bounds__(256) void gemm_out_kernel(
    const float* __restrict__ agg2, const float* __restrict__ W2,
    const float* __restrict__ b2, float* __restrict__ out, int N) {
  __shared__ float Wl[64 * 128];  // 32 KB, loaded once
  const int t = threadIdx.x;
  {
    const float4* Wv = (const float4*)W2;
    float4* Wd = (float4*)Wl;
    for (int i = t; i < 64 * 128 / 4; i += 256) Wd[i] = Wv[i];
  }
  __syncthreads();
  const int lane = t & 63;
  const int wid = __builtin_amdgcn_readfirstlane(blockIdx.x * 4 + (t >> 6));
  const int npairs = gridDim.x * 2;          // wave pairs
  const int pair = wid >> 1;
  const int col = (wid & 1) * 64 + lane;     // 0..127
  const float bc = b2[col];
  for (int row4 = pair * 4; row4 < N; row4 += npairs * 4) {
    const int r0 = row4;
    const int r1 = min(row4 + 1, N - 1);
    const int r2 = min(row4 + 2, N - 1);
    const int r3 = min(row4 + 3, N - 1);
    const float* __restrict__ x0 = agg2 + (size_t)r0 * 64;
    const float* __restrict__ x1 = agg2 + (size_t)r1 * 64;
    const float* __restrict__ x2 = agg2 + (size_t)r2 * 64;
    const float* __restrict__ x3 = agg2 + (size_t)r3 * 64;
    float a0 = bc, a1 = bc, a2 = bc, a3 = bc;
#pragma unroll 8
    for (int k = 0; k < 64; ++k) {
      float wv = Wl[k * 128 + col];
      a0 = fmaf(x0[k], wv, a0);
      a1 = fmaf(x1[k], wv, a1);
      a2 = fmaf(x2[k], wv, a2);
      a3 = fmaf(x3[k], wv, a3);
    }
    if (r0 < N) out[(size_t)r0 * 128 + col] = a0;
    if (row4 + 1 < N) out[(size_t)r1 * 128 + col] = a1;
    if (row4 + 2 < N) out[(size_t)r2 * 128 + col] = a2;
    if (row4 + 3 < N) out[(size_t)r3 * 128 + col] = a3;
  }
}

extern "C" void kernel_launch(void* const* d_in, const int* in_sizes, int n_in,
                              void* d_out, int out_size, void* d_ws, size_t ws_size,
                              hipStream_t stream) {
  const float* x    = (const float*)d_in[0];
  const int*   ei   = (const int*)d_in[1];
  const float* W1   = (const float*)d_in[2];
  const float* a_s1 = (const float*)d_in[3];
  const float* a_d1 = (const float*)d_in[4];
  const float* b1   = (const float*)d_in[5];
  const float* W2   = (const float*)d_in[6];
  const float* a_s2 = (const float*)d_in[7];
  const float* a_d2 = (const float*)d_in[8];
  const float* b2   = (const float*)d_in[9];

  const int N  = in_sizes[0] / 128;
  const int E  = in_sizes[1] / 2;
  const int ET = E + N;
  const int* srcs = ei;
  const int* dsts = ei + E;
  const int nblk = (N + 255) / 256;

  // workspace layout
  char* w = (char*)d_ws;
  __half* h16  = (__half*)w;            w += (size_t)N * 64 * 2;
  __half* rl1  = (__half*)w;            w += (size_t)N * 64 * 2;
  float* agg2  = (float*)w;             w += (size_t)N * 64 * 4;
  float* as1   = (float*)w;             w += (size_t)N * 4;
  float* ad1   = (float*)w;             w += (size_t)N * 4;
  float* as2   = (float*)w;             w += (size_t)N * 4;
  float* ad2   = (float*)w;             w += (size_t)N * 4;
  float* w2as  = (float*)w;             w += 64 * 4;
  float* w2ad  = (float*)w;             w += 64 * 4;
  int* row_ptr = (int*)w;               w += (size_t)(N + 1) * 4;
  int* next    = (int*)w;               w += (size_t)N * 4;
  int* ssrc    = (int*)w;               w += (size_t)ET * 4;
  int* sdst    = (int*)w;               w += (size_t)ET * 4;
  float* pe    = (float*)w;             w += (size_t)ET * 4;
  int* bsums   = (int*)w;               w += (size_t)nblk * 4;
  int* count   = next;  // alias: histogram is dead after scan

  float* out = (float*)d_out;  // N*128

  // ---- build CSR skeleton (independent of features) ----
  hipMemsetAsync(count, 0, (size_t)N * sizeof(int), stream);
  hist_kernel<<<2048, 256, 0, stream>>>(dsts, E, ET, count);
  scan_blocks_kernel<<<nblk, 256, 0, stream>>>(count, row_ptr, bsums, N);
  scan_top_kernel<<<1, 256, 0, stream>>>(bsums, nblk);
  scan_add_kernel<<<nblk, 256, 0, stream>>>(row_ptr, bsums, next, N, ET);

  // ---- weights prep + layer-1 features ----
  prep_kernel<<<1, 128, 0, stream>>>(W2, a_s2, a_d2, w2as, w2ad);
  gemm1_kernel<<<1024, 256, 0, stream>>>(x, W1, a_s1, a_d1, h16, as1, ad1, N);
  // ---- scatter (sorted adjacency) + layer-1 edge weights ----
  scatter_pe1_kernel<<<2048, 256, 0, stream>>>(srcs, dsts, E, ET, next, as1, ad1,
                                               ssrc, sdst, pe);
  // ---- layer-1 aggregation ----
  node_agg_kernel<1><<<(N + 3) / 4, 256, 0, stream>>>(
      row_ptr, ssrc, pe, h16, b1, w2as, w2ad, rl1, as2, ad2, (float*)nullptr, N);
  // ---- layer-2 edge weights + aggregation (64-dim, W2 commuted out) ----
  edge_p2_kernel<<<2048, 256, 0, stream>>>(ssrc, sdst, ET, as2, ad2, pe);
  node_agg_kernel<2><<<(N + 3) / 4, 256, 0, stream>>>(
      row_ptr, ssrc, pe, rl1, b1, w2as, w2ad, ((__half*)nullptr), as2, ad2,
      agg2, N);
  // ---- final GEMM ----
  gemm_out_kernel<<<1024, 256, 0, stream>>>(agg2, W2, b2, out, N);
}